// Round 7
// baseline (1318.323 us; speedup 1.0000x reference)
//
#include <hip/hip_runtime.h>
#include <math.h>

#define NN 50000      // nodes
#define NE 1000000    // edges
#define D 64          // hidden
#define FIN 19
#define EHD 50        // edge attr dim
#define NG 128        // graphs
#define NBLK 3
#define NB1 196       // (NN+255)/256

#define PI_OVER_CUT 0.6283185307179586f
#define LN2F 0.6931471805599453f

static __device__ __forceinline__ float sspf(float x) {
  return fmaxf(x, 0.0f) + log1pf(expf(-fabsf(x))) - LN2F;
}
static __device__ __forceinline__ float sigm(float x) {
  return 1.0f / (1.0f + expf(-x));
}

// ---- degree count ----
__global__ __launch_bounds__(256) void k_deg(const int* __restrict__ ei,
                                             int* __restrict__ degi) {
  int e = blockIdx.x * 256 + threadIdx.x;
  if (e < NE) atomicAdd(&degi[ei[NE + e]], 1);
}

// ---- parallel scan pass 1 ----
__global__ __launch_bounds__(256) void k_scan1(int* __restrict__ degi,
                                               int* __restrict__ start,
                                               float* __restrict__ dinv,
                                               int* __restrict__ bsum) {
  __shared__ int sc[256];
  int t = threadIdx.x;
  int i = blockIdx.x * 256 + t;
  int d = (i < NN) ? degi[i] : 0;
  sc[t] = d; __syncthreads();
  for (int off = 1; off < 256; off <<= 1) {
    int u = (t >= off) ? sc[t - off] : 0;
    __syncthreads();
    sc[t] += u;
    __syncthreads();
  }
  if (i < NN) {
    start[i] = sc[t] - d;
    dinv[i] = 1.0f / fmaxf((float)d, 1.0f);
    degi[i] = 0;                          // becomes cursor for k_slot2
  }
  if (t == 255) bsum[blockIdx.x] = sc[255];
}

// ---- scan pass 2 ----
__global__ __launch_bounds__(256) void k_scan2(int* __restrict__ bsum) {
  __shared__ int sc[256];
  int t = threadIdx.x;
  int v = (t < NB1) ? bsum[t] : 0;
  sc[t] = v; __syncthreads();
  for (int off = 1; off < 256; off <<= 1) {
    int u = (t >= off) ? sc[t - off] : 0;
    __syncthreads();
    sc[t] += u;
    __syncthreads();
  }
  bsum[t] = sc[t] - v;
}

// ---- scan pass 3 ----
__global__ __launch_bounds__(256) void k_scan3(int* __restrict__ start,
                                               const int* __restrict__ bsum) {
  int i = blockIdx.x * 256 + threadIdx.x;
  if (i < NN) start[i] += bsum[blockIdx.x];
  if (i == 0) start[NN] = NE;
}

// ---- CSR slot assignment: es/ssrc/sdst/Cp in slot order ----
__global__ __launch_bounds__(256) void k_slot2(const int* __restrict__ ei,
                                               const float* __restrict__ ew,
                                               const int* __restrict__ start,
                                               int* __restrict__ cursor,
                                               int* __restrict__ es,
                                               int* __restrict__ ssrc,
                                               int* __restrict__ sdst,
                                               float* __restrict__ Cp) {
  int e = blockIdx.x * 256 + threadIdx.x;
  if (e >= NE) return;
  int dst = ei[NE + e];
  int ofs = atomicAdd(&cursor[dst], 1);
  int s = start[dst] + ofs;
  es[s] = e;
  ssrc[s] = ei[e];
  sdst[s] = dst;
  Cp[s] = cosf(ew[e] * PI_OVER_CUT) * 0.5f + 0.5f;
}

// ---- graph boundaries ----
__global__ void k_bounds(const int* __restrict__ batch, int* __restrict__ bounds) {
  int g = threadIdx.x;
  if (g > NG) return;
  int lo = 0, hi = NN;
  while (lo < hi) { int mid = (lo + hi) >> 1; if (batch[mid] < g) lo = mid + 1; else hi = mid; }
  bounds[g] = lo;
}

// ---- lin0 quarter-split ----
__global__ __launch_bounds__(256) void k_lin0q(const float* __restrict__ x,
                                               const float* __restrict__ w,
                                               const float* __restrict__ bias,
                                               float* __restrict__ S) {
  int n = blockIdx.x * 256 + threadIdx.x;
  int q = blockIdx.y;
  if (n >= NN) return;
  float xr[FIN];
  #pragma unroll
  for (int k = 0; k < FIN; k++) xr[k] = x[n * FIN + k];
  #pragma unroll
  for (int i = 0; i < 16; i++) {
    int d = q * 16 + i;
    float a0 = bias[d], a1 = 0.f;
    #pragma unroll
    for (int k = 0; k < FIN - 1; k += 2) {
      a0 += xr[k] * w[d * FIN + k];
      a1 += xr[k + 1] * w[d * FIN + k + 1];
    }
    a0 += xr[FIN - 1] * w[d * FIN + FIN - 1];
    float acc = a0 + a1;
    S[(size_t)n * D + d] = acc > 0.f ? acc : 0.01f * acc;
  }
}

// ---- tiled GEMV stage (initial hx only) ----
template<int ACT>
__global__ __launch_bounds__(256) void k_stage(const float* __restrict__ in,
                                               const float* __restrict__ w,
                                               const float* __restrict__ bias,
                                               float* __restrict__ out) {
  __shared__ float tile[64 * 65];
  int tid = threadIdx.x;
  long nb = (long)blockIdx.x * 64;
  const float4* src = (const float4*)(in + nb * D);
  #pragma unroll
  for (int r = 0; r < 4; r++) {
    int idx = r * 256 + tid;
    int row = idx >> 4, c4 = idx & 15;
    float4 v = src[idx];
    float* dp = &tile[row * 65 + c4 * 4];
    dp[0] = v.x; dp[1] = v.y; dp[2] = v.z; dp[3] = v.w;
  }
  __syncthreads();
  int q = __builtin_amdgcn_readfirstlane(tid >> 6);
  int lane = tid & 63;
  float acc[16];
  const float* wr = w + q * 16 * D;
  #pragma unroll
  for (int i = 0; i < 16; i++) acc[i] = bias ? bias[q * 16 + i] : 0.0f;
  for (int k = 0; k < D; k++) {
    float a = tile[lane * 65 + k];
    #pragma unroll
    for (int i = 0; i < 16; i++) acc[i] += a * wr[i * D + k];
  }
  __syncthreads();
  #pragma unroll
  for (int i = 0; i < 16; i++) {
    float v = acc[i];
    if (ACT == 1) v = sspf(v);
    tile[lane * 65 + q * 16 + i] = v;
  }
  __syncthreads();
  float4* dst = (float4*)(out + nb * D);
  #pragma unroll
  for (int r = 0; r < 4; r++) {
    int idx = r * 256 + tid;
    int row = idx >> 4, c4 = idx & 15;
    if (nb + row < NN) {
      const float* sp = &tile[row * 65 + c4 * 4];
      dst[idx] = make_float4(sp[0], sp[1], sp[2], sp[3]);
    }
  }
}

// ---- fully fused edge conv: 4 waves/block, wave = 64 CSR slots ----
// 8-dim chunks: LDS = 8x68 floats/wave (2176 B) so ~7 WGs/CU fit the LDS
// allocation pool -> ~28 resident waves/CU (was ~14 with 16-dim chunks).
// MLP1+MLP2 in registers (s_load weights); wave-private tile for segmented
// reduce; consecutive-address atomic bursts at segment boundaries only.
__global__ __launch_bounds__(256) void k_econv(const float* __restrict__ ea,
                                               const float* __restrict__ w1,
                                               const float* __restrict__ b1,
                                               const float* __restrict__ w2,
                                               const float* __restrict__ b2,
                                               const float* __restrict__ Cp,
                                               const int* __restrict__ es,
                                               const int* __restrict__ ssrc,
                                               const int* __restrict__ sdst,
                                               const float* __restrict__ hx,
                                               float* __restrict__ agg) {
  __shared__ float tileAll[4 * 8 * 68];    // 8704 B per 4-wave WG
  int tid = threadIdx.x;
  int wid = tid >> 6, lane = tid & 63;
  float* tile = tileAll + wid * (8 * 68);
  int s = blockIdx.x * 256 + tid;
  if (s >= NE) return;                     // whole trailing waves exit
  int e = es[s];
  int srcn = ssrc[s];
  int me = sdst[s];
  float cv = Cp[s];
  // within-wave segment boundaries (sdst non-decreasing in slot order)
  int pm = __shfl_up(me, 1);
  bool bound = (lane == 0) || (me != pm);
  unsigned long long segmask = __ballot(bound);   // per-wave mask
  // load ea row: 50 floats (200B rows, 8B aligned)
  float arr[EHD];
  const float2* er = (const float2*)(ea + (size_t)e * EHD);
  #pragma unroll
  for (int k2 = 0; k2 < EHD / 2; k2++) {
    float2 v = er[k2];
    arr[2 * k2] = v.x; arr[2 * k2 + 1] = v.y;
  }
  // MLP1: t1 = relu(arr @ w1^T + b1)
  float t1[32];
  #pragma unroll
  for (int j = 0; j < 32; j++) {
    float a0 = b1[j], a1 = 0.f;
    #pragma unroll
    for (int k = 0; k < EHD; k += 2) {
      a0 += arr[k]     * w1[j * EHD + k];
      a1 += arr[k + 1] * w1[j * EHD + k + 1];
    }
    t1[j] = fmaxf(a0 + a1, 0.0f);
  }
  const float4* hrow = (const float4*)(hx + (size_t)srcn * D);
  int dim = lane >> 3, r = lane & 7;       // 8 dims x 8 reducers
  #pragma unroll
  for (int c = 0; c < 8; c++) {
    float4 hv0 = hrow[c * 2];
    float4 hv1 = hrow[c * 2 + 1];
    float mg[8];
    #pragma unroll
    for (int u = 0; u < 8; u++) {
      int d = c * 8 + u;
      float a0 = b2[d], a1 = 0, a2 = 0, a3 = 0;
      #pragma unroll
      for (int j = 0; j < 32; j += 4) {
        a0 += t1[j]     * w2[d * 32 + j];
        a1 += t1[j + 1] * w2[d * 32 + j + 1];
        a2 += t1[j + 2] * w2[d * 32 + j + 2];
        a3 += t1[j + 3] * w2[d * 32 + j + 3];
      }
      float4 h4 = (u < 4) ? hv0 : hv1;
      float hc = (u & 3) == 0 ? h4.x : (u & 3) == 1 ? h4.y
               : (u & 3) == 2 ? h4.z : h4.w;
      mg[u] = ((a0 + a1) + (a2 + a3)) * cv * hc;
    }
    #pragma unroll
    for (int u = 0; u < 8; u++) tile[u * 68 + lane] = mg[u];
    asm volatile("s_waitcnt lgkmcnt(0)" ::: "memory");
    // wave-synchronous segmented reduce
    unsigned long long mask = segmask;
    while (mask) {
      int l0 = __ffsll((unsigned long long)mask) - 1;
      unsigned long long rest = mask & (mask - 1);
      int l1 = rest ? (__ffsll((unsigned long long)rest) - 1) : 64;
      mask = rest;
      int node = __shfl(me, l0);
      float v = 0.f;
      for (int sl = l0 + r; sl < l1; sl += 8)
        v += tile[dim * 68 + sl];
      v += __shfl_xor(v, 1);
      v += __shfl_xor(v, 2);
      v += __shfl_xor(v, 4);
      if (r == 0)
        atomicAdd(&agg[(size_t)node * D + c * 8 + dim], v);
    }
    asm volatile("s_waitcnt lgkmcnt(0)" ::: "memory");
  }
}

// ---- fused node pipeline: (agg*dinv)->lin2+ssp->lin3->GRU->next hx ----
__global__ __launch_bounds__(256) void k_nodeblk(const float* __restrict__ agg,
                                                 const float* __restrict__ dinv,
                                                 const float* __restrict__ hin,
                                                 const float* __restrict__ w2,
                                                 const float* __restrict__ b2,
                                                 const float* __restrict__ w3,
                                                 const float* __restrict__ b3,
                                                 const float* __restrict__ wih,
                                                 const float* __restrict__ whh,
                                                 const float* __restrict__ bih,
                                                 const float* __restrict__ bhh,
                                                 float* __restrict__ hout,
                                                 const float* __restrict__ w1n,
                                                 float* __restrict__ hxout) {
  __shared__ float tA[64 * 65];
  __shared__ float tH[64 * 65];
  int tid = threadIdx.x;
  long nb = (long)blockIdx.x * 64;
  const float4* as = (const float4*)(agg + nb * D);
  const float4* hs = (const float4*)(hin + nb * D);
  #pragma unroll
  for (int r = 0; r < 4; r++) {
    int idx = r * 256 + tid;
    int row = idx >> 4, c4 = idx & 15;
    float dv = dinv[nb + row];
    float4 v = as[idx];
    float* dp = &tA[row * 65 + c4 * 4];
    dp[0] = v.x * dv; dp[1] = v.y * dv; dp[2] = v.z * dv; dp[3] = v.w * dv;
    float4 u = hs[idx];
    float* ep = &tH[row * 65 + c4 * 4];
    ep[0] = u.x; ep[1] = u.y; ep[2] = u.z; ep[3] = u.w;
  }
  __syncthreads();
  int q = __builtin_amdgcn_readfirstlane(tid >> 6);
  int lane = tid & 63;
  // phase 1: v1 = ssp(agg @ w2^T + b2)
  {
    float acc[16];
    const float* wr = w2 + q * 16 * D;
    #pragma unroll
    for (int i = 0; i < 16; i++) acc[i] = b2[q * 16 + i];
    for (int k = 0; k < D; k++) {
      float a = tA[lane * 65 + k];
      #pragma unroll
      for (int i = 0; i < 16; i++) acc[i] += a * wr[i * D + k];
    }
    __syncthreads();
    #pragma unroll
    for (int i = 0; i < 16; i++) tA[lane * 65 + q * 16 + i] = sspf(acc[i]);
    __syncthreads();
  }
  // phase 2: m = v1 @ w3^T + b3
  {
    float acc[16];
    const float* wr = w3 + q * 16 * D;
    #pragma unroll
    for (int i = 0; i < 16; i++) acc[i] = b3[q * 16 + i];
    for (int k = 0; k < D; k++) {
      float a = tA[lane * 65 + k];
      #pragma unroll
      for (int i = 0; i < 16; i++) acc[i] += a * wr[i * D + k];
    }
    __syncthreads();
    #pragma unroll
    for (int i = 0; i < 16; i++) tA[lane * 65 + q * 16 + i] = acc[i];
    __syncthreads();
  }
  // phase 3: GRU
  {
    float ir[16], iz[16], inn[16], hr[16], hz[16], hn[16];
    #pragma unroll
    for (int i = 0; i < 16; i++) {
      int dd = q * 16 + i;
      ir[i] = bih[dd]; iz[i] = bih[D + dd]; inn[i] = bih[2 * D + dd];
      hr[i] = bhh[dd]; hz[i] = bhh[D + dd]; hn[i] = bhh[2 * D + dd];
    }
    const float* wi0 = wih + q * 16 * D;
    const float* wi1 = wih + (D + q * 16) * D;
    const float* wi2 = wih + (2 * D + q * 16) * D;
    const float* wh0 = whh + q * 16 * D;
    const float* wh1 = whh + (D + q * 16) * D;
    const float* wh2 = whh + (2 * D + q * 16) * D;
    for (int k = 0; k < D; k++) {
      float mm = tA[lane * 65 + k];
      float hh = tH[lane * 65 + k];
      #pragma unroll
      for (int i = 0; i < 16; i++) {
        ir[i]  += mm * wi0[i * D + k];
        iz[i]  += mm * wi1[i * D + k];
        inn[i] += mm * wi2[i * D + k];
        hr[i]  += hh * wh0[i * D + k];
        hz[i]  += hh * wh1[i * D + k];
        hn[i]  += hh * wh2[i * D + k];
      }
    }
    __syncthreads();
    #pragma unroll
    for (int i = 0; i < 16; i++) {
      float hold = tH[lane * 65 + q * 16 + i];
      float r = sigm(ir[i] + hr[i]);
      float zg = sigm(iz[i] + hz[i]);
      float nn2 = tanhf(inn[i] + r * hn[i]);
      tA[lane * 65 + q * 16 + i] = (1.0f - zg) * nn2 + zg * hold;
    }
    __syncthreads();
  }
  // store h'
  float4* dst = (float4*)(hout + nb * D);
  #pragma unroll
  for (int r = 0; r < 4; r++) {
    int idx = r * 256 + tid;
    int row = idx >> 4, c4 = idx & 15;
    if (nb + row < NN) {
      const float* sp = &tA[row * 65 + c4 * 4];
      dst[idx] = make_float4(sp[0], sp[1], sp[2], sp[3]);
    }
  }
  // phase 4: next-block hx = h' @ w1n^T
  if (w1n) {
    float acc[16];
    const float* wr = w1n + q * 16 * D;
    #pragma unroll
    for (int i = 0; i < 16; i++) acc[i] = 0.0f;
    for (int k = 0; k < D; k++) {
      float a = tA[lane * 65 + k];
      #pragma unroll
      for (int i = 0; i < 16; i++) acc[i] += a * wr[i * D + k];
    }
    __syncthreads();
    #pragma unroll
    for (int i = 0; i < 16; i++) tH[lane * 65 + q * 16 + i] = acc[i];
    __syncthreads();
    float4* dh = (float4*)(hxout + nb * D);
    #pragma unroll
    for (int r = 0; r < 4; r++) {
      int idx = r * 256 + tid;
      int row = idx >> 4, c4 = idx & 15;
      if (nb + row < NN) {
        const float* sp = &tH[row * 65 + c4 * 4];
        dh[idx] = make_float4(sp[0], sp[1], sp[2], sp[3]);
      }
    }
  }
}

// ---- fused Set2Set step: per-graph LSTM (threads<64) then attention ----
__global__ __launch_bounds__(256) void k_s2s(const float* __restrict__ wih,
                                             const float* __restrict__ whh,
                                             const float* __restrict__ bih,
                                             const float* __restrict__ bhh,
                                             const float* __restrict__ S,
                                             const int* __restrict__ bounds,
                                             float* __restrict__ qstar,
                                             float* __restrict__ hl,
                                             float* __restrict__ cl,
                                             float* __restrict__ ebuf) {
  __shared__ float qv[D];
  __shared__ float red[256];
  int g = blockIdx.x, tid = threadIdx.x;
  // ---- LSTM phase (one wave) ----
  if (tid < D) {
    int d = tid;
    const float* qs = qstar + g * 2 * D;
    const float* hr = hl + g * D;
    float ai = bih[d]         + bhh[d];
    float af = bih[D + d]     + bhh[D + d];
    float ag = bih[2 * D + d] + bhh[2 * D + d];
    float ao = bih[3 * D + d] + bhh[3 * D + d];
    #pragma unroll 8
    for (int k = 0; k < 2 * D; k++) {
      float q = qs[k];
      ai += q * wih[d * 2 * D + k];
      af += q * wih[(D + d) * 2 * D + k];
      ag += q * wih[(2 * D + d) * 2 * D + k];
      ao += q * wih[(3 * D + d) * 2 * D + k];
    }
    #pragma unroll 8
    for (int k = 0; k < D; k++) {
      float h = hr[k];
      ai += h * whh[d * D + k];
      af += h * whh[(D + d) * D + k];
      ag += h * whh[(2 * D + d) * D + k];
      ao += h * whh[(3 * D + d) * D + k];
    }
    float c = sigm(af) * cl[g * D + d] + sigm(ai) * tanhf(ag);
    float hn = sigm(ao) * tanhf(c);
    cl[g * D + d] = c;
    hl[g * D + d] = hn;
    qstar[g * 2 * D + d] = hn;
    qv[d] = hn;
  }
  __syncthreads();
  // ---- attention phase ----
  int s = bounds[g], en = bounds[g + 1];
  float lmax = -1e30f;
  for (int n = s + tid; n < en; n += 256) {
    const float4* Sv = (const float4*)(S + (size_t)n * D);
    float a0 = 0, a1 = 0, a2 = 0, a3 = 0;
    #pragma unroll
    for (int q = 0; q < 16; q++) {
      float4 v = Sv[q];
      a0 += v.x * qv[4*q]; a1 += v.y * qv[4*q+1];
      a2 += v.z * qv[4*q+2]; a3 += v.w * qv[4*q+3];
    }
    float e = (a0 + a1) + (a2 + a3);
    ebuf[n] = e;
    lmax = fmaxf(lmax, e);
  }
  red[tid] = lmax; __syncthreads();
  for (int st = 128; st > 0; st >>= 1) {
    if (tid < st) red[tid] = fmaxf(red[tid], red[tid + st]);
    __syncthreads();
  }
  float smax = red[0]; __syncthreads();
  float lsum = 0;
  for (int n = s + tid; n < en; n += 256) {
    float p = expf(ebuf[n] - smax);
    ebuf[n] = p;
    lsum += p;
  }
  red[tid] = lsum; __syncthreads();
  for (int st = 128; st > 0; st >>= 1) {
    if (tid < st) red[tid] += red[tid + st];
    __syncthreads();
  }
  float inv = red[0] > 0.f ? 1.0f / red[0] : 0.0f;
  __syncthreads();
  int grp = tid >> 6, d = tid & 63;
  float acc = 0;
  for (int n = s + grp; n < en; n += 4)
    acc += ebuf[n] * S[(size_t)n * D + d];
  red[tid] = acc; __syncthreads();
  if (tid < D)
    qstar[g * 2 * D + D + tid] =
        (red[tid] + red[64 + tid] + red[128 + tid] + red[192 + tid]) * inv;
}

// ---- final head ----
__global__ __launch_bounds__(64) void k_final(const float* __restrict__ qstar,
                                              const float* __restrict__ w1,
                                              const float* __restrict__ b1,
                                              const float* __restrict__ w2,
                                              const float* __restrict__ b2,
                                              const int* __restrict__ z,
                                              const float* __restrict__ eref,
                                              const float* __restrict__ aref,
                                              const int* __restrict__ bounds,
                                              float* __restrict__ outp) {
  __shared__ float red[D];
  int g = blockIdx.x, d = threadIdx.x;
  const float* qs = qstar + g * 2 * D;
  float a0 = 0, a1 = 0, a2 = 0, a3 = 0;
  #pragma unroll
  for (int k = 0; k < 2 * D; k += 4) {
    a0 += qs[k]   * w1[d * 2 * D + k];
    a1 += qs[k+1] * w1[d * 2 * D + k + 1];
    a2 += qs[k+2] * w1[d * 2 * D + k + 2];
    a3 += qs[k+3] * w1[d * 2 * D + k + 3];
  }
  float gv = fmaxf((a0 + a1) + (a2 + a3) + b1[d], 0.0f);
  red[d] = gv * w2[d];
  __syncthreads();
  for (int st = 32; st > 0; st >>= 1) {
    if (d < st) red[d] += red[d + st];
    __syncthreads();
  }
  float energy = red[0] + b2[0];
  __syncthreads();
  int s = bounds[g], en = bounds[g + 1];
  float racc = 0;
  for (int n = s + d; n < en; n += 64) {
    int zz = z[n];
    racc += eref[zz] + aref[zz];
  }
  red[d] = racc; __syncthreads();
  for (int st = 32; st > 0; st >>= 1) {
    if (d < st) red[d] += red[d + st];
    __syncthreads();
  }
  if (d == 0) outp[g] = energy + red[0];
}

extern "C" void kernel_launch(void* const* d_in, const int* in_sizes, int n_in,
                              void* d_out, int out_size, void* d_ws, size_t ws_size,
                              hipStream_t stream) {
  const float* x      = (const float*)d_in[0];
  const int*   ei     = (const int*)d_in[1];
  const float* ew     = (const float*)d_in[2];
  const float* ea     = (const float*)d_in[3];
  const int*   z      = (const int*)d_in[4];
  const int*   batch  = (const int*)d_in[5];
  const float* lin0_w = (const float*)d_in[6];
  const float* lin0_b = (const float*)d_in[7];
  const float* cw1    = (const float*)d_in[8];
  const float* cb1    = (const float*)d_in[9];
  const float* cw2    = (const float*)d_in[10];
  const float* cb2    = (const float*)d_in[11];
  const float* cl1w   = (const float*)d_in[12];
  const float* cl2w   = (const float*)d_in[13];
  const float* cl2b   = (const float*)d_in[14];
  const float* cl3w   = (const float*)d_in[15];
  const float* cl3b   = (const float*)d_in[16];
  const float* gwih   = (const float*)d_in[17];
  const float* gwhh   = (const float*)d_in[18];
  const float* gbih   = (const float*)d_in[19];
  const float* gbhh   = (const float*)d_in[20];
  const float* lwih   = (const float*)d_in[21];
  const float* lwhh   = (const float*)d_in[22];
  const float* lbih   = (const float*)d_in[23];
  const float* lbhh   = (const float*)d_in[24];
  const float* l1w    = (const float*)d_in[25];
  const float* l1b    = (const float*)d_in[26];
  const float* l2w    = (const float*)d_in[27];
  const float* l2b    = (const float*)d_in[28];
  const float* aref   = (const float*)d_in[29];
  const float* eref   = (const float*)d_in[30];
  float* outp = (float*)d_out;

  const long NND = (long)NN * D;
  float* f = (float*)d_ws;
  long cur = 0;
  long oS0 = cur;   cur += NND;
  long oS1 = cur;   cur += NND;
  long oHX = cur;   cur += NND;
  long oAG = cur;   cur += NND;
  long oCP = cur;   cur += NE;
  long oDI = cur;   cur += 50176;
  long oEB = cur;   cur += 50176;  // ebuf / degi(cursor)
  long oQ  = cur;   cur += NG * 2 * D;
  long oHL = cur;   cur += NG * D;
  long oCL = cur;   cur += NG * D;
  long oBN = cur;   cur += 256;
  long oES = cur;   cur += NE;
  long oSR = cur;   cur += NE;
  long oSD = cur;   cur += NE;
  long oST = cur;   cur += 51200;
  long oBS = cur;   cur += 256;

  float* S0   = f + oS0;
  float* S1   = f + oS1;
  float* hxb  = f + oHX;
  float* aggb = f + oAG;
  float* Cp   = f + oCP;
  float* dinv = f + oDI;
  float* ebuf = f + oEB;
  int*   degi = (int*)(f + oEB);
  float* qstar= f + oQ;
  float* hl   = f + oHL;
  float* cls  = f + oCL;
  int*   bounds = (int*)(f + oBN);
  int*   es   = (int*)(f + oES);
  int*   ssrc = (int*)(f + oSR);
  int*   sdst = (int*)(f + oSD);
  int*   startA = (int*)(f + oST);
  int*   bsum = (int*)(f + oBS);

  hipMemsetAsync(degi, 0, NN * sizeof(int), stream);
  hipMemsetAsync(qstar, 0, (NG * 2 * D + 2 * NG * D) * sizeof(float), stream);

  k_deg<<<(NE + 255) / 256, 256, 0, stream>>>(ei, degi);
  k_scan1<<<NB1, 256, 0, stream>>>(degi, startA, dinv, bsum);
  k_scan2<<<1, 256, 0, stream>>>(bsum);
  k_scan3<<<NB1, 256, 0, stream>>>(startA, bsum);
  k_slot2<<<(NE + 255) / 256, 256, 0, stream>>>(ei, ew, startA, degi, es, ssrc,
                                                sdst, Cp);
  k_lin0q<<<dim3((NN + 255) / 256, 4), 256, 0, stream>>>(x, lin0_w, lin0_b, S0);
  k_bounds<<<1, 192, 0, stream>>>(batch, bounds);

  const int NBK = (NN + 63) / 64;
  k_stage<0><<<NBK, 256, 0, stream>>>(S0, cl1w, nullptr, hxb);

  for (int b = 0; b < NBLK; b++) {
    float* Sin  = (b & 1) ? S1 : S0;
    float* Sout = (b & 1) ? S0 : S1;
    hipMemsetAsync(aggb, 0, NND * sizeof(float), stream);
    k_econv<<<(NE + 255) / 256, 256, 0, stream>>>(
        ea, cw1 + b * 32 * EHD, cb1 + b * 32, cw2 + b * D * 32, cb2 + b * D,
        Cp, es, ssrc, sdst, hxb, aggb);
    const float* w1n = (b + 1 < NBLK) ? (cl1w + (b + 1) * D * D) : nullptr;
    k_nodeblk<<<NBK, 256, 0, stream>>>(aggb, dinv, Sin,
                                       cl2w + b * D * D, cl2b + b * D,
                                       cl3w + b * D * D, cl3b + b * D,
                                       gwih, gwhh, gbih, gbhh,
                                       Sout, w1n, hxb);
  }

  float* Sfin = (NBLK & 1) ? S1 : S0;
  for (int it = 0; it < 3; it++) {
    k_s2s<<<NG, 256, 0, stream>>>(lwih, lwhh, lbih, lbhh, Sfin, bounds,
                                  qstar, hl, cls, ebuf);
  }

  k_final<<<NG, 64, 0, stream>>>(qstar, l1w, l1b, l2w, l2b, z, eref, aref,
                                 bounds, outp);
}

// Round 8
// 1226.709 us; speedup vs baseline: 1.0747x; 1.0747x over previous
//
#include <hip/hip_runtime.h>
#include <math.h>

#define NN 50000      // nodes
#define NE 1000000    // edges
#define D 64          // hidden
#define FIN 19
#define EHD 50        // edge attr dim
#define NG 128        // graphs
#define NBLK 3
#define NB1 196       // (NN+255)/256

#define PI_OVER_CUT 0.6283185307179586f
#define LN2F 0.6931471805599453f

static __device__ __forceinline__ float sspf(float x) {
  return fmaxf(x, 0.0f) + log1pf(expf(-fabsf(x))) - LN2F;
}
static __device__ __forceinline__ float sigm(float x) {
  return 1.0f / (1.0f + expf(-x));
}
// round-to-nearest-even bf16 pair pack (inputs are finite, >= 0 post-ReLU)
static __device__ __forceinline__ unsigned int bf16pair(float a, float b) {
  unsigned int ua = __float_as_uint(a);
  unsigned int ub = __float_as_uint(b);
  ua = (ua + 0x7FFFu + ((ua >> 16) & 1u)) >> 16;
  ub = (ub + 0x7FFFu + ((ub >> 16) & 1u)) & 0xFFFF0000u;
  return ua | ub;
}

// ---- degree count ----
__global__ __launch_bounds__(256) void k_deg(const int* __restrict__ ei,
                                             int* __restrict__ degi) {
  int e = blockIdx.x * 256 + threadIdx.x;
  if (e < NE) atomicAdd(&degi[ei[NE + e]], 1);
}

// ---- parallel scan pass 1 ----
__global__ __launch_bounds__(256) void k_scan1(int* __restrict__ degi,
                                               int* __restrict__ start,
                                               float* __restrict__ dinv,
                                               int* __restrict__ bsum) {
  __shared__ int sc[256];
  int t = threadIdx.x;
  int i = blockIdx.x * 256 + t;
  int d = (i < NN) ? degi[i] : 0;
  sc[t] = d; __syncthreads();
  for (int off = 1; off < 256; off <<= 1) {
    int u = (t >= off) ? sc[t - off] : 0;
    __syncthreads();
    sc[t] += u;
    __syncthreads();
  }
  if (i < NN) {
    start[i] = sc[t] - d;
    dinv[i] = 1.0f / fmaxf((float)d, 1.0f);
    degi[i] = 0;                          // becomes cursor for k_slot2
  }
  if (t == 255) bsum[blockIdx.x] = sc[255];
}

// ---- scan pass 2 ----
__global__ __launch_bounds__(256) void k_scan2(int* __restrict__ bsum) {
  __shared__ int sc[256];
  int t = threadIdx.x;
  int v = (t < NB1) ? bsum[t] : 0;
  sc[t] = v; __syncthreads();
  for (int off = 1; off < 256; off <<= 1) {
    int u = (t >= off) ? sc[t - off] : 0;
    __syncthreads();
    sc[t] += u;
    __syncthreads();
  }
  bsum[t] = sc[t] - v;
}

// ---- scan pass 3 ----
__global__ __launch_bounds__(256) void k_scan3(int* __restrict__ start,
                                               const int* __restrict__ bsum) {
  int i = blockIdx.x * 256 + threadIdx.x;
  if (i < NN) start[i] += bsum[blockIdx.x];
  if (i == 0) start[NN] = NE;
}

// ---- CSR slot assignment: inv/ssrc/sdst/Cp ----
__global__ __launch_bounds__(256) void k_slot2(const int* __restrict__ ei,
                                               const float* __restrict__ ew,
                                               const int* __restrict__ start,
                                               int* __restrict__ cursor,
                                               int* __restrict__ inv,
                                               int* __restrict__ ssrc,
                                               int* __restrict__ sdst,
                                               float* __restrict__ Cp) {
  int e = blockIdx.x * 256 + threadIdx.x;
  if (e >= NE) return;
  int dst = ei[NE + e];
  int ofs = atomicAdd(&cursor[dst], 1);
  int s = start[dst] + ofs;
  inv[e] = s;
  ssrc[s] = ei[e];
  sdst[s] = dst;
  Cp[s] = cosf(ew[e] * PI_OVER_CUT) * 0.5f + 0.5f;
}

// ---- graph boundaries ----
__global__ void k_bounds(const int* __restrict__ batch, int* __restrict__ bounds) {
  int g = threadIdx.x;
  if (g > NG) return;
  int lo = 0, hi = NN;
  while (lo < hi) { int mid = (lo + hi) >> 1; if (batch[mid] < g) lo = mid + 1; else hi = mid; }
  bounds[g] = lo;
}

// ---- lin0 quarter-split ----
__global__ __launch_bounds__(256) void k_lin0q(const float* __restrict__ x,
                                               const float* __restrict__ w,
                                               const float* __restrict__ bias,
                                               float* __restrict__ S) {
  int n = blockIdx.x * 256 + threadIdx.x;
  int q = blockIdx.y;
  if (n >= NN) return;
  float xr[FIN];
  #pragma unroll
  for (int k = 0; k < FIN; k++) xr[k] = x[n * FIN + k];
  #pragma unroll
  for (int i = 0; i < 16; i++) {
    int d = q * 16 + i;
    float a0 = bias[d], a1 = 0.f;
    #pragma unroll
    for (int k = 0; k < FIN - 1; k += 2) {
      a0 += xr[k] * w[d * FIN + k];
      a1 += xr[k + 1] * w[d * FIN + k + 1];
    }
    a0 += xr[FIN - 1] * w[d * FIN + FIN - 1];
    float acc = a0 + a1;
    S[(size_t)n * D + d] = acc > 0.f ? acc : 0.01f * acc;
  }
}

// ---- tiled GEMV stage (initial hx only) ----
template<int ACT>
__global__ __launch_bounds__(256) void k_stage(const float* __restrict__ in,
                                               const float* __restrict__ w,
                                               const float* __restrict__ bias,
                                               float* __restrict__ out) {
  __shared__ float tile[64 * 65];
  int tid = threadIdx.x;
  long nb = (long)blockIdx.x * 64;
  const float4* src = (const float4*)(in + nb * D);
  #pragma unroll
  for (int r = 0; r < 4; r++) {
    int idx = r * 256 + tid;
    int row = idx >> 4, c4 = idx & 15;
    float4 v = src[idx];
    float* dp = &tile[row * 65 + c4 * 4];
    dp[0] = v.x; dp[1] = v.y; dp[2] = v.z; dp[3] = v.w;
  }
  __syncthreads();
  int q = __builtin_amdgcn_readfirstlane(tid >> 6);
  int lane = tid & 63;
  float acc[16];
  const float* wr = w + q * 16 * D;
  #pragma unroll
  for (int i = 0; i < 16; i++) acc[i] = bias ? bias[q * 16 + i] : 0.0f;
  for (int k = 0; k < D; k++) {
    float a = tile[lane * 65 + k];
    #pragma unroll
    for (int i = 0; i < 16; i++) acc[i] += a * wr[i * D + k];
  }
  __syncthreads();
  #pragma unroll
  for (int i = 0; i < 16; i++) {
    float v = acc[i];
    if (ACT == 1) v = sspf(v);
    tile[lane * 65 + q * 16 + i] = v;
  }
  __syncthreads();
  float4* dst = (float4*)(out + nb * D);
  #pragma unroll
  for (int r = 0; r < 4; r++) {
    int idx = r * 256 + tid;
    int row = idx >> 4, c4 = idx & 15;
    if (nb + row < NN) {
      const float* sp = &tile[row * 65 + c4 * 4];
      dst[idx] = make_float4(sp[0], sp[1], sp[2], sp[3]);
    }
  }
}

// ---- dense edge MLP1 for nb conv-blocks in one ea pass ----
// stages 64 ea rows once, computes T1_b = relu(ea@W1_b^T+b1_b) for each b,
// stores bf16-packed rows (64B) in CSR slot order via inv[e].
__global__ __launch_bounds__(256) void k_mlp1x3(const float* __restrict__ ea,
                                                const float* __restrict__ w1all,
                                                const float* __restrict__ b1all,
                                                const int* __restrict__ inv,
                                                unsigned int* __restrict__ T1,
                                                int nb) {
  __shared__ float tile[64 * 51];
  __shared__ float outT[64 * 33];
  int tid = threadIdx.x;
  long eb = (long)blockIdx.x * 64;       // NE % 64 == 0
  const float* src = ea + eb * EHD;
  #pragma unroll
  for (int it = 0; it < 13; it++) {
    int idx = it * 256 + tid;
    if (idx < 64 * EHD) {
      int row = idx / EHD, col = idx - row * EHD;
      tile[row * 51 + col] = src[idx];   // coalesced
    }
  }
  int q = __builtin_amdgcn_readfirstlane(tid >> 6);
  int lane = tid & 63;
  int row = tid >> 2, q4 = tid & 3;
  int srow = inv[eb + row];
  unsigned int* T1r = T1;
  for (int b = 0; b < nb; b++) {
    const float* wr = w1all + b * 32 * EHD + q * 8 * EHD;
    const float* br = b1all + b * 32;
    float acc[8];
    #pragma unroll
    for (int i = 0; i < 8; i++) acc[i] = br[q * 8 + i];
    __syncthreads();   // b=0: stage done; b>0: prior outT readers done
    for (int k = 0; k < EHD; k++) {
      float a = tile[lane * 51 + k];
      #pragma unroll
      for (int i = 0; i < 8; i++) acc[i] += a * wr[i * EHD + k];
    }
    #pragma unroll
    for (int i = 0; i < 8; i++) outT[lane * 33 + q * 8 + i] = fmaxf(acc[i], 0.0f);
    __syncthreads();
    const float* sp = &outT[row * 33 + q4 * 8];
    uint4 o;
    o.x = bf16pair(sp[0], sp[1]);
    o.y = bf16pair(sp[2], sp[3]);
    o.z = bf16pair(sp[4], sp[5]);
    o.w = bf16pair(sp[6], sp[7]);
    ((uint4*)(T1r + (size_t)srow * 16))[q4] = o;  // 4 lanes/row -> 64B burst
    T1r += (size_t)NE * 16;
  }
}

// ---- edge conv stage 2: coalesced bf16 T1 + MLP2 + segmented aggregate ----
// round-6 16-dim-chunk structure (0 bank conflicts), ea gather and MLP1 gone.
__global__ __launch_bounds__(256) void k_econv2(const unsigned int* __restrict__ T1,
                                                const float* __restrict__ w2,
                                                const float* __restrict__ b2,
                                                const float* __restrict__ Cp,
                                                const int* __restrict__ ssrc,
                                                const int* __restrict__ sdst,
                                                const float* __restrict__ hx,
                                                float* __restrict__ agg) {
  __shared__ float tileAll[4 * 16 * 68];
  int tid = threadIdx.x;
  int wid = tid >> 6, lane = tid & 63;
  float* tile = tileAll + wid * (16 * 68);
  int s = blockIdx.x * 256 + tid;
  if (s >= NE) return;
  int srcn = ssrc[s];
  int me = sdst[s];
  float cv = Cp[s];
  int pm = __shfl_up(me, 1);
  bool bound = (lane == 0) || (me != pm);
  unsigned long long segmask = __ballot(bound);
  // T1 row: 32 bf16 in 16 uints, contiguous per slot (wave reads 4KB stream)
  const uint4* tp = (const uint4*)(T1 + (size_t)s * 16);
  uint4 u0 = tp[0], u1 = tp[1], u2 = tp[2], u3 = tp[3];
  float t1[32];
  {
    unsigned int w_[16] = {u0.x, u0.y, u0.z, u0.w, u1.x, u1.y, u1.z, u1.w,
                           u2.x, u2.y, u2.z, u2.w, u3.x, u3.y, u3.z, u3.w};
    #pragma unroll
    for (int j = 0; j < 16; j++) {
      t1[2 * j]     = __uint_as_float(w_[j] << 16);
      t1[2 * j + 1] = __uint_as_float(w_[j] & 0xFFFF0000u);
    }
  }
  const float4* hrow = (const float4*)(hx + (size_t)srcn * D);
  int dim = lane >> 2, r = lane & 3;
  #pragma unroll
  for (int c = 0; c < 4; c++) {
    float4 hv[4];
    #pragma unroll
    for (int i = 0; i < 4; i++) hv[i] = hrow[c * 4 + i];
    float mg[16];
    #pragma unroll
    for (int u = 0; u < 16; u++) {
      int d = c * 16 + u;
      float a0 = b2[d], a1 = 0, a2 = 0, a3 = 0;
      #pragma unroll
      for (int j = 0; j < 32; j += 4) {
        a0 += t1[j]     * w2[d * 32 + j];
        a1 += t1[j + 1] * w2[d * 32 + j + 1];
        a2 += t1[j + 2] * w2[d * 32 + j + 2];
        a3 += t1[j + 3] * w2[d * 32 + j + 3];
      }
      float4 h4 = hv[u >> 2];
      float hc = (u & 3) == 0 ? h4.x : (u & 3) == 1 ? h4.y
               : (u & 3) == 2 ? h4.z : h4.w;
      mg[u] = ((a0 + a1) + (a2 + a3)) * cv * hc;
    }
    #pragma unroll
    for (int u = 0; u < 16; u++) tile[u * 68 + lane] = mg[u];
    asm volatile("s_waitcnt lgkmcnt(0)" ::: "memory");
    unsigned long long mask = segmask;
    while (mask) {
      int l0 = __ffsll((unsigned long long)mask) - 1;
      unsigned long long rest = mask & (mask - 1);
      int l1 = rest ? (__ffsll((unsigned long long)rest) - 1) : 64;
      mask = rest;
      int node = __shfl(me, l0);
      float v = 0.f;
      for (int sl = l0 + r; sl < l1; sl += 4)
        v += tile[dim * 68 + sl];
      v += __shfl_xor(v, 1);
      v += __shfl_xor(v, 2);
      if (r == 0)
        atomicAdd(&agg[(size_t)node * D + c * 16 + dim], v);
    }
    asm volatile("s_waitcnt lgkmcnt(0)" ::: "memory");
  }
}

// ---- fused node pipeline: (agg*dinv)->lin2+ssp->lin3->GRU->next hx ----
__global__ __launch_bounds__(256) void k_nodeblk(const float* __restrict__ agg,
                                                 const float* __restrict__ dinv,
                                                 const float* __restrict__ hin,
                                                 const float* __restrict__ w2,
                                                 const float* __restrict__ b2,
                                                 const float* __restrict__ w3,
                                                 const float* __restrict__ b3,
                                                 const float* __restrict__ wih,
                                                 const float* __restrict__ whh,
                                                 const float* __restrict__ bih,
                                                 const float* __restrict__ bhh,
                                                 float* __restrict__ hout,
                                                 const float* __restrict__ w1n,
                                                 float* __restrict__ hxout) {
  __shared__ float tA[64 * 65];
  __shared__ float tH[64 * 65];
  int tid = threadIdx.x;
  long nb = (long)blockIdx.x * 64;
  const float4* as = (const float4*)(agg + nb * D);
  const float4* hs = (const float4*)(hin + nb * D);
  #pragma unroll
  for (int r = 0; r < 4; r++) {
    int idx = r * 256 + tid;
    int row = idx >> 4, c4 = idx & 15;
    float dv = dinv[nb + row];
    float4 v = as[idx];
    float* dp = &tA[row * 65 + c4 * 4];
    dp[0] = v.x * dv; dp[1] = v.y * dv; dp[2] = v.z * dv; dp[3] = v.w * dv;
    float4 u = hs[idx];
    float* ep = &tH[row * 65 + c4 * 4];
    ep[0] = u.x; ep[1] = u.y; ep[2] = u.z; ep[3] = u.w;
  }
  __syncthreads();
  int q = __builtin_amdgcn_readfirstlane(tid >> 6);
  int lane = tid & 63;
  {
    float acc[16];
    const float* wr = w2 + q * 16 * D;
    #pragma unroll
    for (int i = 0; i < 16; i++) acc[i] = b2[q * 16 + i];
    for (int k = 0; k < D; k++) {
      float a = tA[lane * 65 + k];
      #pragma unroll
      for (int i = 0; i < 16; i++) acc[i] += a * wr[i * D + k];
    }
    __syncthreads();
    #pragma unroll
    for (int i = 0; i < 16; i++) tA[lane * 65 + q * 16 + i] = sspf(acc[i]);
    __syncthreads();
  }
  {
    float acc[16];
    const float* wr = w3 + q * 16 * D;
    #pragma unroll
    for (int i = 0; i < 16; i++) acc[i] = b3[q * 16 + i];
    for (int k = 0; k < D; k++) {
      float a = tA[lane * 65 + k];
      #pragma unroll
      for (int i = 0; i < 16; i++) acc[i] += a * wr[i * D + k];
    }
    __syncthreads();
    #pragma unroll
    for (int i = 0; i < 16; i++) tA[lane * 65 + q * 16 + i] = acc[i];
    __syncthreads();
  }
  {
    float ir[16], iz[16], inn[16], hr[16], hz[16], hn[16];
    #pragma unroll
    for (int i = 0; i < 16; i++) {
      int dd = q * 16 + i;
      ir[i] = bih[dd]; iz[i] = bih[D + dd]; inn[i] = bih[2 * D + dd];
      hr[i] = bhh[dd]; hz[i] = bhh[D + dd]; hn[i] = bhh[2 * D + dd];
    }
    const float* wi0 = wih + q * 16 * D;
    const float* wi1 = wih + (D + q * 16) * D;
    const float* wi2 = wih + (2 * D + q * 16) * D;
    const float* wh0 = whh + q * 16 * D;
    const float* wh1 = whh + (D + q * 16) * D;
    const float* wh2 = whh + (2 * D + q * 16) * D;
    for (int k = 0; k < D; k++) {
      float mm = tA[lane * 65 + k];
      float hh = tH[lane * 65 + k];
      #pragma unroll
      for (int i = 0; i < 16; i++) {
        ir[i]  += mm * wi0[i * D + k];
        iz[i]  += mm * wi1[i * D + k];
        inn[i] += mm * wi2[i * D + k];
        hr[i]  += hh * wh0[i * D + k];
        hz[i]  += hh * wh1[i * D + k];
        hn[i]  += hh * wh2[i * D + k];
      }
    }
    __syncthreads();
    #pragma unroll
    for (int i = 0; i < 16; i++) {
      float hold = tH[lane * 65 + q * 16 + i];
      float r = sigm(ir[i] + hr[i]);
      float zg = sigm(iz[i] + hz[i]);
      float nn2 = tanhf(inn[i] + r * hn[i]);
      tA[lane * 65 + q * 16 + i] = (1.0f - zg) * nn2 + zg * hold;
    }
    __syncthreads();
  }
  float4* dst = (float4*)(hout + nb * D);
  #pragma unroll
  for (int r = 0; r < 4; r++) {
    int idx = r * 256 + tid;
    int row = idx >> 4, c4 = idx & 15;
    if (nb + row < NN) {
      const float* sp = &tA[row * 65 + c4 * 4];
      dst[idx] = make_float4(sp[0], sp[1], sp[2], sp[3]);
    }
  }
  if (w1n) {
    float acc[16];
    const float* wr = w1n + q * 16 * D;
    #pragma unroll
    for (int i = 0; i < 16; i++) acc[i] = 0.0f;
    for (int k = 0; k < D; k++) {
      float a = tA[lane * 65 + k];
      #pragma unroll
      for (int i = 0; i < 16; i++) acc[i] += a * wr[i * D + k];
    }
    __syncthreads();
    #pragma unroll
    for (int i = 0; i < 16; i++) tH[lane * 65 + q * 16 + i] = acc[i];
    __syncthreads();
    float4* dh = (float4*)(hxout + nb * D);
    #pragma unroll
    for (int r = 0; r < 4; r++) {
      int idx = r * 256 + tid;
      int row = idx >> 4, c4 = idx & 15;
      if (nb + row < NN) {
        const float* sp = &tH[row * 65 + c4 * 4];
        dh[idx] = make_float4(sp[0], sp[1], sp[2], sp[3]);
      }
    }
  }
}

// ---- fused Set2Set step ----
__global__ __launch_bounds__(256) void k_s2s(const float* __restrict__ wih,
                                             const float* __restrict__ whh,
                                             const float* __restrict__ bih,
                                             const float* __restrict__ bhh,
                                             const float* __restrict__ S,
                                             const int* __restrict__ bounds,
                                             float* __restrict__ qstar,
                                             float* __restrict__ hl,
                                             float* __restrict__ cl,
                                             float* __restrict__ ebuf) {
  __shared__ float qv[D];
  __shared__ float red[256];
  int g = blockIdx.x, tid = threadIdx.x;
  if (tid < D) {
    int d = tid;
    const float* qs = qstar + g * 2 * D;
    const float* hr = hl + g * D;
    float ai = bih[d]         + bhh[d];
    float af = bih[D + d]     + bhh[D + d];
    float ag = bih[2 * D + d] + bhh[2 * D + d];
    float ao = bih[3 * D + d] + bhh[3 * D + d];
    #pragma unroll 8
    for (int k = 0; k < 2 * D; k++) {
      float q = qs[k];
      ai += q * wih[d * 2 * D + k];
      af += q * wih[(D + d) * 2 * D + k];
      ag += q * wih[(2 * D + d) * 2 * D + k];
      ao += q * wih[(3 * D + d) * 2 * D + k];
    }
    #pragma unroll 8
    for (int k = 0; k < D; k++) {
      float h = hr[k];
      ai += h * whh[d * D + k];
      af += h * whh[(D + d) * D + k];
      ag += h * whh[(2 * D + d) * D + k];
      ao += h * whh[(3 * D + d) * D + k];
    }
    float c = sigm(af) * cl[g * D + d] + sigm(ai) * tanhf(ag);
    float hn = sigm(ao) * tanhf(c);
    cl[g * D + d] = c;
    hl[g * D + d] = hn;
    qstar[g * 2 * D + d] = hn;
    qv[d] = hn;
  }
  __syncthreads();
  int s = bounds[g], en = bounds[g + 1];
  float lmax = -1e30f;
  for (int n = s + tid; n < en; n += 256) {
    const float4* Sv = (const float4*)(S + (size_t)n * D);
    float a0 = 0, a1 = 0, a2 = 0, a3 = 0;
    #pragma unroll
    for (int q = 0; q < 16; q++) {
      float4 v = Sv[q];
      a0 += v.x * qv[4*q]; a1 += v.y * qv[4*q+1];
      a2 += v.z * qv[4*q+2]; a3 += v.w * qv[4*q+3];
    }
    float e = (a0 + a1) + (a2 + a3);
    ebuf[n] = e;
    lmax = fmaxf(lmax, e);
  }
  red[tid] = lmax; __syncthreads();
  for (int st = 128; st > 0; st >>= 1) {
    if (tid < st) red[tid] = fmaxf(red[tid], red[tid + st]);
    __syncthreads();
  }
  float smax = red[0]; __syncthreads();
  float lsum = 0;
  for (int n = s + tid; n < en; n += 256) {
    float p = expf(ebuf[n] - smax);
    ebuf[n] = p;
    lsum += p;
  }
  red[tid] = lsum; __syncthreads();
  for (int st = 128; st > 0; st >>= 1) {
    if (tid < st) red[tid] += red[tid + st];
    __syncthreads();
  }
  float inv = red[0] > 0.f ? 1.0f / red[0] : 0.0f;
  __syncthreads();
  int grp = tid >> 6, d = tid & 63;
  float acc = 0;
  for (int n = s + grp; n < en; n += 4)
    acc += ebuf[n] * S[(size_t)n * D + d];
  red[tid] = acc; __syncthreads();
  if (tid < D)
    qstar[g * 2 * D + D + tid] =
        (red[tid] + red[64 + tid] + red[128 + tid] + red[192 + tid]) * inv;
}

// ---- final head ----
__global__ __launch_bounds__(64) void k_final(const float* __restrict__ qstar,
                                              const float* __restrict__ w1,
                                              const float* __restrict__ b1,
                                              const float* __restrict__ w2,
                                              const float* __restrict__ b2,
                                              const int* __restrict__ z,
                                              const float* __restrict__ eref,
                                              const float* __restrict__ aref,
                                              const int* __restrict__ bounds,
                                              float* __restrict__ outp) {
  __shared__ float red[D];
  int g = blockIdx.x, d = threadIdx.x;
  const float* qs = qstar + g * 2 * D;
  float a0 = 0, a1 = 0, a2 = 0, a3 = 0;
  #pragma unroll
  for (int k = 0; k < 2 * D; k += 4) {
    a0 += qs[k]   * w1[d * 2 * D + k];
    a1 += qs[k+1] * w1[d * 2 * D + k + 1];
    a2 += qs[k+2] * w1[d * 2 * D + k + 2];
    a3 += qs[k+3] * w1[d * 2 * D + k + 3];
  }
  float gv = fmaxf((a0 + a1) + (a2 + a3) + b1[d], 0.0f);
  red[d] = gv * w2[d];
  __syncthreads();
  for (int st = 32; st > 0; st >>= 1) {
    if (d < st) red[d] += red[d + st];
    __syncthreads();
  }
  float energy = red[0] + b2[0];
  __syncthreads();
  int s = bounds[g], en = bounds[g + 1];
  float racc = 0;
  for (int n = s + d; n < en; n += 64) {
    int zz = z[n];
    racc += eref[zz] + aref[zz];
  }
  red[d] = racc; __syncthreads();
  for (int st = 32; st > 0; st >>= 1) {
    if (d < st) red[d] += red[d + st];
    __syncthreads();
  }
  if (d == 0) outp[g] = energy + red[0];
}

extern "C" void kernel_launch(void* const* d_in, const int* in_sizes, int n_in,
                              void* d_out, int out_size, void* d_ws, size_t ws_size,
                              hipStream_t stream) {
  const float* x      = (const float*)d_in[0];
  const int*   ei     = (const int*)d_in[1];
  const float* ew     = (const float*)d_in[2];
  const float* ea     = (const float*)d_in[3];
  const int*   z      = (const int*)d_in[4];
  const int*   batch  = (const int*)d_in[5];
  const float* lin0_w = (const float*)d_in[6];
  const float* lin0_b = (const float*)d_in[7];
  const float* cw1    = (const float*)d_in[8];
  const float* cb1    = (const float*)d_in[9];
  const float* cw2    = (const float*)d_in[10];
  const float* cb2    = (const float*)d_in[11];
  const float* cl1w   = (const float*)d_in[12];
  const float* cl2w   = (const float*)d_in[13];
  const float* cl2b   = (const float*)d_in[14];
  const float* cl3w   = (const float*)d_in[15];
  const float* cl3b   = (const float*)d_in[16];
  const float* gwih   = (const float*)d_in[17];
  const float* gwhh   = (const float*)d_in[18];
  const float* gbih   = (const float*)d_in[19];
  const float* gbhh   = (const float*)d_in[20];
  const float* lwih   = (const float*)d_in[21];
  const float* lwhh   = (const float*)d_in[22];
  const float* lbih   = (const float*)d_in[23];
  const float* lbhh   = (const float*)d_in[24];
  const float* l1w    = (const float*)d_in[25];
  const float* l1b    = (const float*)d_in[26];
  const float* l2w    = (const float*)d_in[27];
  const float* l2b    = (const float*)d_in[28];
  const float* aref   = (const float*)d_in[29];
  const float* eref   = (const float*)d_in[30];
  float* outp = (float*)d_out;

  const long NND = (long)NN * D;
  float* f = (float*)d_ws;
  long cur = 0;
  long oS0 = cur;   cur += NND;
  long oS1 = cur;   cur += NND;
  long oHX = cur;   cur += NND;
  long oAG = cur;   cur += NND;
  long oCP = cur;   cur += NE;
  long oDI = cur;   cur += 50176;
  long oEB = cur;   cur += 50176;  // ebuf / degi(cursor)
  long oQ  = cur;   cur += NG * 2 * D;
  long oHL = cur;   cur += NG * D;
  long oCL = cur;   cur += NG * D;
  long oBN = cur;   cur += 256;
  long oIV = cur;   cur += NE;
  long oSR = cur;   cur += NE;
  long oSD = cur;   cur += NE;
  long oST = cur;   cur += 51200;
  long oBS = cur;   cur += 256;
  long baseEnd = cur;

  float* S0   = f + oS0;
  float* S1   = f + oS1;
  float* hxb  = f + oHX;
  float* aggb = f + oAG;
  float* Cp   = f + oCP;
  float* dinv = f + oDI;
  float* ebuf = f + oEB;
  int*   degi = (int*)(f + oEB);
  float* qstar= f + oQ;
  float* hl   = f + oHL;
  float* cls  = f + oCL;
  int*   bounds = (int*)(f + oBN);
  int*   inv  = (int*)(f + oIV);
  int*   ssrc = (int*)(f + oSR);
  int*   sdst = (int*)(f + oSD);
  int*   startA = (int*)(f + oST);
  int*   bsum = (int*)(f + oBS);

  // T1 buffers: bf16-packed, NE*16 uints per conv-block; 3 if ws allows
  long wsF = (long)(ws_size / 4);
  long t1need = (long)NE * 16;   // 4B units
  int nT1 = (baseEnd + 3 * t1need <= wsF) ? 3 : 1;
  unsigned int* T1 = (unsigned int*)(f + baseEnd);

  hipMemsetAsync(degi, 0, NN * sizeof(int), stream);
  hipMemsetAsync(qstar, 0, (NG * 2 * D + 2 * NG * D) * sizeof(float), stream);

  k_deg<<<(NE + 255) / 256, 256, 0, stream>>>(ei, degi);
  k_scan1<<<NB1, 256, 0, stream>>>(degi, startA, dinv, bsum);
  k_scan2<<<1, 256, 0, stream>>>(bsum);
  k_scan3<<<NB1, 256, 0, stream>>>(startA, bsum);
  k_slot2<<<(NE + 255) / 256, 256, 0, stream>>>(ei, ew, startA, degi, inv, ssrc,
                                                sdst, Cp);
  k_lin0q<<<dim3((NN + 255) / 256, 4), 256, 0, stream>>>(x, lin0_w, lin0_b, S0);
  k_bounds<<<1, 192, 0, stream>>>(batch, bounds);

  if (nT1 == 3)   // one pass over ea computes all 3 blocks' T1
    k_mlp1x3<<<NE / 64, 256, 0, stream>>>(ea, cw1, cb1, inv, T1, 3);

  const int NBK = (NN + 63) / 64;
  k_stage<0><<<NBK, 256, 0, stream>>>(S0, cl1w, nullptr, hxb);

  for (int b = 0; b < NBLK; b++) {
    float* Sin  = (b & 1) ? S1 : S0;
    float* Sout = (b & 1) ? S0 : S1;
    if (nT1 == 1)
      k_mlp1x3<<<NE / 64, 256, 0, stream>>>(ea, cw1 + b * 32 * EHD,
                                            cb1 + b * 32, inv, T1, 1);
    hipMemsetAsync(aggb, 0, NND * sizeof(float), stream);
    unsigned int* T1b = T1 + (size_t)(nT1 == 3 ? b : 0) * NE * 16;
    k_econv2<<<(NE + 255) / 256, 256, 0, stream>>>(
        T1b, cw2 + b * D * 32, cb2 + b * D, Cp, ssrc, sdst, hxb, aggb);
    const float* w1n = (b + 1 < NBLK) ? (cl1w + (b + 1) * D * D) : nullptr;
    k_nodeblk<<<NBK, 256, 0, stream>>>(aggb, dinv, Sin,
                                       cl2w + b * D * D, cl2b + b * D,
                                       cl3w + b * D * D, cl3b + b * D,
                                       gwih, gwhh, gbih, gbhh,
                                       Sout, w1n, hxb);
  }

  float* Sfin = (NBLK & 1) ? S1 : S0;
  for (int it = 0; it < 3; it++) {
    k_s2s<<<NG, 256, 0, stream>>>(lwih, lwhh, lbih, lbhh, Sfin, bounds,
                                  qstar, hl, cls, ebuf);
  }

  k_final<<<NG, 64, 0, stream>>>(qstar, l1w, l1b, l2w, l2b, z, eref, aref,
                                 bounds, outp);
}